// Round 1
// baseline (49.602 us; speedup 1.0000x reference)
//
#include <hip/hip_runtime.h>

#define N 512
#define BLK 256
#define MARGIN 1.0f

// d_ws layout: [0] float loss accumulator, [1] uint pair-count accumulator
__global__ __launch_bounds__(BLK) void ranking_loss_pairs(
    const float* __restrict__ pred,
    const int* __restrict__ rank,
    float* __restrict__ loss_acc,
    unsigned int* __restrict__ cnt_acc)
{
    __shared__ float sp[N];
    __shared__ int   sr[N];
    const int b = blockIdx.x;
    const int t = threadIdx.x;

    // stage this batch row: 512 preds + 512 ranks
    for (int k = t; k < N; k += BLK) {
        sp[k] = pred[b * N + k];
        sr[k] = rank[b * N + k];
    }
    __syncthreads();

    const int   i0 = t;
    const int   i1 = t + BLK;
    const float p0 = sp[i0];
    const float p1 = sp[i1];
    const int   r0 = sr[i0];
    const int   r1 = sr[i1];

    float loss = 0.0f;
    int   cnt  = 0;

#pragma unroll 4
    for (int j = 0; j < N; ++j) {
        const float pj = sp[j];   // broadcast read — all lanes same addr
        const int   rj = sr[j];
        // pair (i0, j)
        {
            const float pd = p0 - pj;
            const bool gt = (r0 > rj);
            const bool eq = (r0 == rj) & (i0 != j);
            const float h = fmaxf(MARGIN + pd, 0.0f);
            loss += gt ? h : (eq ? pd * pd : 0.0f);
            cnt  += (int)gt + (int)eq;
        }
        // pair (i1, j)
        {
            const float pd = p1 - pj;
            const bool gt = (r1 > rj);
            const bool eq = (r1 == rj) & (i1 != j);
            const float h = fmaxf(MARGIN + pd, 0.0f);
            loss += gt ? h : (eq ? pd * pd : 0.0f);
            cnt  += (int)gt + (int)eq;
        }
    }

    // wave (64-lane) reduction
    for (int off = 32; off > 0; off >>= 1) {
        loss += __shfl_down(loss, off, 64);
        cnt  += __shfl_down(cnt,  off, 64);
    }

    __shared__ float redf[BLK / 64];
    __shared__ int   redi[BLK / 64];
    const int wave = t >> 6;
    const int lane = t & 63;
    if (lane == 0) { redf[wave] = loss; redi[wave] = cnt; }
    __syncthreads();
    if (t == 0) {
        float L = redf[0] + redf[1] + redf[2] + redf[3];
        int   C = redi[0] + redi[1] + redi[2] + redi[3];
        atomicAdd(loss_acc, L);
        atomicAdd(cnt_acc, (unsigned int)C);
    }
}

__global__ void ranking_loss_finalize(const float* __restrict__ loss_acc,
                                      const unsigned int* __restrict__ cnt_acc,
                                      float* __restrict__ out)
{
    out[0] = loss_acc[0] / ((float)cnt_acc[0] + 1e-8f);
}

extern "C" void kernel_launch(void* const* d_in, const int* in_sizes, int n_in,
                              void* d_out, int out_size, void* d_ws, size_t ws_size,
                              hipStream_t stream)
{
    const float* pred = (const float*)d_in[0];
    const int*   rank = (const int*)d_in[1];
    float*        loss_acc = (float*)d_ws;
    unsigned int* cnt_acc  = (unsigned int*)((char*)d_ws + 4);

    const int B = in_sizes[0] / N;   // 256

    hipMemsetAsync(d_ws, 0, 8, stream);
    ranking_loss_pairs<<<B, BLK, 0, stream>>>(pred, rank, loss_acc, cnt_acc);
    ranking_loss_finalize<<<1, 1, 0, stream>>>(loss_acc, cnt_acc, (float*)d_out);
}

// Round 2
// 42.547 us; speedup vs baseline: 1.1658x; 1.1658x over previous
//
#include <hip/hip_runtime.h>

#define N 512
#define BLKT 512          // one thread per i
#define JC 4              // j-chunks per row
#define JLEN (N / JC)     // 128
#define MARGIN 1.0f

// d_ws layout: [0] float loss accumulator, [1] uint pair-count accumulator
__global__ __launch_bounds__(BLKT) void ranking_loss_pairs(
    const float* __restrict__ pred,
    const int* __restrict__ rank,
    float* __restrict__ loss_acc,
    unsigned int* __restrict__ cnt_acc)
{
    __shared__ float sp[JLEN];
    __shared__ int   sr[JLEN];
    const int blk = blockIdx.x;
    const int b   = blk >> 2;      // batch row
    const int q   = blk & 3;       // j-chunk index
    const int j0  = q * JLEN;
    const int t   = threadIdx.x;   // i = t

    // stage this row's j-chunk (broadcast source for all i)
    if (t < JLEN) {
        sp[t] = pred[b * N + j0 + t];
        sr[t] = rank[b * N + j0 + t];
    }
    const float pi = pred[b * N + t];
    const int   ri = rank[b * N + t];
    __syncthreads();

    // 4 rotating loss accumulators + 2 count accumulators -> break dep chains
    float l0 = 0.f, l1 = 0.f, l2 = 0.f, l3 = 0.f;
    int   c0 = 0, c1 = 0;

#pragma unroll 8
    for (int j = 0; j < JLEN; j += 4) {
        {
            const float pd = pi - sp[j + 0];
            const int   rj = sr[j + 0];
            const bool  gt = (ri > rj), eq = (ri == rj);
            const float h  = fmaxf(pd + MARGIN, 0.0f);
            l0 += gt ? h : (eq ? pd * pd : 0.0f);
            c0 += (int)gt + (int)eq;
        }
        {
            const float pd = pi - sp[j + 1];
            const int   rj = sr[j + 1];
            const bool  gt = (ri > rj), eq = (ri == rj);
            const float h  = fmaxf(pd + MARGIN, 0.0f);
            l1 += gt ? h : (eq ? pd * pd : 0.0f);
            c1 += (int)gt + (int)eq;
        }
        {
            const float pd = pi - sp[j + 2];
            const int   rj = sr[j + 2];
            const bool  gt = (ri > rj), eq = (ri == rj);
            const float h  = fmaxf(pd + MARGIN, 0.0f);
            l2 += gt ? h : (eq ? pd * pd : 0.0f);
            c0 += (int)gt + (int)eq;
        }
        {
            const float pd = pi - sp[j + 3];
            const int   rj = sr[j + 3];
            const bool  gt = (ri > rj), eq = (ri == rj);
            const float h  = fmaxf(pd + MARGIN, 0.0f);
            l3 += gt ? h : (eq ? pd * pd : 0.0f);
            c1 += (int)gt + (int)eq;
        }
    }

    float loss = (l0 + l1) + (l2 + l3);
    int   cnt  = c0 + c1;
    // diagonal j==i lives in this chunk iff j0 <= i < j0+JLEN:
    // it is an eq-pair with pd==0 -> 0 loss, +1 count. Remove the count.
    if (t >= j0 && t < j0 + JLEN) cnt -= 1;

    // 64-lane wave reduction
    for (int off = 32; off > 0; off >>= 1) {
        loss += __shfl_down(loss, off, 64);
        cnt  += __shfl_down(cnt,  off, 64);
    }

    __shared__ float redf[BLKT / 64];
    __shared__ int   redi[BLKT / 64];
    const int wave = t >> 6;
    const int lane = t & 63;
    if (lane == 0) { redf[wave] = loss; redi[wave] = cnt; }
    __syncthreads();
    if (t == 0) {
        float L = 0.f; int C = 0;
#pragma unroll
        for (int w = 0; w < BLKT / 64; ++w) { L += redf[w]; C += redi[w]; }
        atomicAdd(loss_acc, L);
        atomicAdd(cnt_acc, (unsigned int)C);
    }
}

__global__ void ranking_loss_finalize(const float* __restrict__ loss_acc,
                                      const unsigned int* __restrict__ cnt_acc,
                                      float* __restrict__ out)
{
    out[0] = loss_acc[0] / ((float)cnt_acc[0] + 1e-8f);
}

extern "C" void kernel_launch(void* const* d_in, const int* in_sizes, int n_in,
                              void* d_out, int out_size, void* d_ws, size_t ws_size,
                              hipStream_t stream)
{
    const float* pred = (const float*)d_in[0];
    const int*   rank = (const int*)d_in[1];
    float*        loss_acc = (float*)d_ws;
    unsigned int* cnt_acc  = (unsigned int*)((char*)d_ws + 4);

    const int B = in_sizes[0] / N;   // 256

    hipMemsetAsync(d_ws, 0, 8, stream);
    ranking_loss_pairs<<<B * JC, BLKT, 0, stream>>>(pred, rank, loss_acc, cnt_acc);
    ranking_loss_finalize<<<1, 1, 0, stream>>>(loss_acc, cnt_acc, (float*)d_out);
}

// Round 3
// 26.018 us; speedup vs baseline: 1.9064x; 1.6352x over previous
//
#include <hip/hip_runtime.h>

#define N 512
#define BLKT 512          // one thread per i
#define JC 4              // j-chunks per row
#define JLEN (N / JC)     // 128
#define NBLK (256 * JC)   // 1024 blocks
#define MARGIN 1.0f

// d_ws layout: float partial_loss[NBLK] ; unsigned partial_cnt[NBLK]
__global__ __launch_bounds__(BLKT) void ranking_loss_pairs(
    const float* __restrict__ pred,
    const int* __restrict__ rank,
    float* __restrict__ part_loss,
    unsigned int* __restrict__ part_cnt)
{
    __shared__ float sp[JLEN];
    __shared__ int   sr[JLEN];
    const int blk = blockIdx.x;
    const int b   = blk >> 2;      // batch row
    const int q   = blk & 3;       // j-chunk index
    const int j0  = q * JLEN;
    const int t   = threadIdx.x;   // i = t

    // stage this row's j-chunk (broadcast source for all i)
    if (t < JLEN) {
        sp[t] = pred[b * N + j0 + t];
        sr[t] = rank[b * N + j0 + t];
    }
    const float pi = pred[b * N + t];
    const int   ri = rank[b * N + t];
    __syncthreads();

    // rotating accumulators -> break dep chains
    float l0 = 0.f, l1 = 0.f, l2 = 0.f, l3 = 0.f;
    int   c0 = 0, c1 = 0;

#pragma unroll 8
    for (int j = 0; j < JLEN; j += 4) {
        {
            const float pd = pi - sp[j + 0];
            const int   rj = sr[j + 0];
            const bool  gt = (ri > rj), eq = (ri == rj);
            const float h  = fmaxf(pd + MARGIN, 0.0f);
            l0 += gt ? h : (eq ? pd * pd : 0.0f);
            c0 += (int)gt + (int)eq;
        }
        {
            const float pd = pi - sp[j + 1];
            const int   rj = sr[j + 1];
            const bool  gt = (ri > rj), eq = (ri == rj);
            const float h  = fmaxf(pd + MARGIN, 0.0f);
            l1 += gt ? h : (eq ? pd * pd : 0.0f);
            c1 += (int)gt + (int)eq;
        }
        {
            const float pd = pi - sp[j + 2];
            const int   rj = sr[j + 2];
            const bool  gt = (ri > rj), eq = (ri == rj);
            const float h  = fmaxf(pd + MARGIN, 0.0f);
            l2 += gt ? h : (eq ? pd * pd : 0.0f);
            c0 += (int)gt + (int)eq;
        }
        {
            const float pd = pi - sp[j + 3];
            const int   rj = sr[j + 3];
            const bool  gt = (ri > rj), eq = (ri == rj);
            const float h  = fmaxf(pd + MARGIN, 0.0f);
            l3 += gt ? h : (eq ? pd * pd : 0.0f);
            c1 += (int)gt + (int)eq;
        }
    }

    float loss = (l0 + l1) + (l2 + l3);
    int   cnt  = c0 + c1;
    // diagonal j==i lives in this chunk iff j0 <= i < j0+JLEN:
    // it is an eq-pair with pd==0 -> 0 loss, +1 count. Remove the count.
    if (t >= j0 && t < j0 + JLEN) cnt -= 1;

    // 64-lane wave reduction
    for (int off = 32; off > 0; off >>= 1) {
        loss += __shfl_down(loss, off, 64);
        cnt  += __shfl_down(cnt,  off, 64);
    }

    __shared__ float redf[BLKT / 64];
    __shared__ int   redi[BLKT / 64];
    const int wave = t >> 6;
    const int lane = t & 63;
    if (lane == 0) { redf[wave] = loss; redi[wave] = cnt; }
    __syncthreads();
    if (t == 0) {
        float L = 0.f; int C = 0;
#pragma unroll
        for (int w = 0; w < BLKT / 64; ++w) { L += redf[w]; C += redi[w]; }
        part_loss[blk] = L;                 // distinct slot per block: no contention
        part_cnt[blk]  = (unsigned int)C;
    }
}

// one block, 1024 threads: reduce the 1024 partials, write final scalar
__global__ __launch_bounds__(NBLK) void ranking_loss_finalize(
    const float* __restrict__ part_loss,
    const unsigned int* __restrict__ part_cnt,
    float* __restrict__ out)
{
    const int t = threadIdx.x;
    float loss = part_loss[t];
    int   cnt  = (int)part_cnt[t];

    for (int off = 32; off > 0; off >>= 1) {
        loss += __shfl_down(loss, off, 64);
        cnt  += __shfl_down(cnt,  off, 64);
    }

    __shared__ float redf[NBLK / 64];
    __shared__ int   redi[NBLK / 64];
    const int wave = t >> 6;
    const int lane = t & 63;
    if (lane == 0) { redf[wave] = loss; redi[wave] = cnt; }
    __syncthreads();
    if (t == 0) {
        float L = 0.f; int C = 0;
#pragma unroll
        for (int w = 0; w < NBLK / 64; ++w) { L += redf[w]; C += redi[w]; }
        out[0] = L / ((float)C + 1e-8f);
    }
}

extern "C" void kernel_launch(void* const* d_in, const int* in_sizes, int n_in,
                              void* d_out, int out_size, void* d_ws, size_t ws_size,
                              hipStream_t stream)
{
    const float* pred = (const float*)d_in[0];
    const int*   rank = (const int*)d_in[1];
    float*        part_loss = (float*)d_ws;
    unsigned int* part_cnt  = (unsigned int*)((char*)d_ws + NBLK * sizeof(float));

    const int B = in_sizes[0] / N;   // 256

    ranking_loss_pairs<<<B * JC, BLKT, 0, stream>>>(pred, rank, part_loss, part_cnt);
    ranking_loss_finalize<<<1, NBLK, 0, stream>>>(part_loss, part_cnt, (float*)d_out);
}